// Round 27
// baseline (114.392 us; speedup 1.0000x reference)
//
#include <hip/hip_runtime.h>
#include <hip/hip_bf16.h>
#include <math.h>

#define EPSF 1e-5f

typedef float f32x4 __attribute__((ext_vector_type(4)));
typedef short short8 __attribute__((ext_vector_type(8)));
typedef short short4v __attribute__((ext_vector_type(4)));
typedef unsigned short u16x4 __attribute__((ext_vector_type(4)));
typedef unsigned short u16x8 __attribute__((ext_vector_type(8)));

#if defined(__has_builtin)
#if __has_builtin(__builtin_amdgcn_mfma_f32_16x16x16bf16_1k)
#define HAVE_MFMA16 1
#endif
#endif
#ifndef HAVE_MFMA16
#define HAVE_MFMA16 0
#endif

static __device__ __forceinline__ unsigned short f2bf(float f) {
    unsigned u = __float_as_uint(f);
    u = (u + 0x7FFF + ((u >> 16) & 1)) >> 16;
    return (unsigned short)u;
}

static __device__ __forceinline__ float bf2f(unsigned short u) {
    return __uint_as_float((unsigned)u << 16);
}

static __device__ __forceinline__ unsigned packbf2(float a, float b) {
    __hip_bfloat162 t = __float22bfloat162_rn(float2{a, b});
    union { __hip_bfloat162 v; unsigned u; } cv;
    cv.v = t;
    return cv.u;
}

// raw v_exp_f32 — NO libm wrapper (exp2f carries denormal handling)
static __device__ __forceinline__ float fexp2(float x) {
    return __builtin_amdgcn_exp2f(x);
}

// Barrier that drains ONLY LDS (lgkmcnt); "memory" clobber orders all
// memory ops. NO sched_barrier so the next tile's global loads can hoist.
static __device__ __forceinline__ void lgkm_barrier() {
    asm volatile("s_waitcnt lgkmcnt(0)\n\ts_barrier" ::: "memory");
}

// XOR-swizzle: spreads 8-byte granules of a row across banks; keeps 16B pairs.
static __device__ __forceinline__ int swz(int r) { return ((r ^ (r >> 2)) & 7) << 1; }

#define ATTN_SCALE 0.17677669529663687f   // 32^-0.5
#define LOG2E      1.4426950408889634f
#define QSCALE     (ATTN_SCALE * LOG2E)   // folded so p = exp2(s) directly

// qhat layout: [half(2)][bh(64)][row(4096)][16 dims]  (bf16)
#define QH_HALF_STRIDE 4194304   // 64*4096*16
// packed bf16 weights: qkv_pw(196608) | out_pw(65536) | mlp_w(65536)
#define WPK_TOTAL 327680

// ---------------------------------------------------------------------------
// Depthwise 3x3 conv (SAME), vectorized 4x8 tile/thread.
// FI: fuse bilinear 64->16 interp of this block's 2 planes + one-time
// grid-strided f32->bf16 weight pack (Wsrc layout: qkv_pw|out_pw|mlp_w).
// ---------------------------------------------------------------------------
template<bool BN, bool IB, bool OBF, bool FI>
__global__ __launch_bounds__(256) void dwconv_k(
    const void* __restrict__ X, const float* __restrict__ DW,
    const float* __restrict__ g, const float* __restrict__ be,
    const float* __restrict__ mn, const float* __restrict__ vr,
    void* __restrict__ Out, float* __restrict__ TR,
    const float* __restrict__ W1, const float* __restrict__ W2,
    const float* __restrict__ W3, unsigned short* __restrict__ Wpk)
{
    extern __shared__ unsigned short pl[];   // FI: [2][64][72] ushort
    int tid = threadIdx.x;

    if (FI) {
        // weight pack: grid-stride over 327680 elements (1024 blocks)
        for (int idx = blockIdx.x * 256 + tid; idx < WPK_TOTAL; idx += 262144) {
            float v = (idx < 196608) ? W1[idx]
                    : (idx < 262144) ? W2[idx - 196608]
                                     : W3[idx - 262144];
            Wpk[idx] = f2bf(v);
        }
    }

    int lp0 = tid >> 7;
    int plane = blockIdx.x * 2 + lp0;
    int c = plane & 255;
    float inv = 1.f, ad = 0.f;
    if (BN) {
        inv = g[c] * rsqrtf(vr[c] + EPSF);
        ad  = be[c] - mn[c] * inv;
    }
    float w[9];
#pragma unroll
    for (int i = 0; i < 9; ++i) w[i] = DW[c * 9 + i];
    const float* Xf          = (const float*)X + (size_t)plane * 4096;
    const unsigned short* Xh = (const unsigned short*)X + (size_t)plane * 4096;
    int u  = tid & 127;
    int y0 = (u >> 3) * 4;
    int x0 = (u & 7) * 8;

    float r[6][16];
#pragma unroll
    for (int rr = 0; rr < 6; ++rr) {
        int yy = y0 + rr - 1;
        bool rv = (unsigned)yy < 64u;
#pragma unroll
        for (int gq = 0; gq < 4; ++gq) {
            int xx = x0 - 4 + gq * 4;
            f32x4 v = {0.f, 0.f, 0.f, 0.f};
            if (rv && (unsigned)xx < 64u) {
                if (IB) {
                    u16x4 u4 = *(const u16x4*)&Xh[yy * 64 + xx];
                    v[0] = bf2f(u4[0]); v[1] = bf2f(u4[1]);
                    v[2] = bf2f(u4[2]); v[3] = bf2f(u4[3]);
                } else {
                    v = *(const f32x4*)&Xf[yy * 64 + xx];
                }
                if (BN) {
#pragma unroll
                    for (int j = 0; j < 4; ++j) v[j] = v[j] * inv + ad;
                }
            }
            r[rr][gq * 4 + 0] = v[0]; r[rr][gq * 4 + 1] = v[1];
            r[rr][gq * 4 + 2] = v[2]; r[rr][gq * 4 + 3] = v[3];
        }
    }

#pragma unroll
    for (int j = 0; j < 4; ++j) {
        float acc[8] = {};
#pragma unroll
        for (int ky = 0; ky < 3; ++ky) {
#pragma unroll
            for (int kx = 0; kx < 3; ++kx) {
                float ww = w[ky * 3 + kx];
#pragma unroll
                for (int p = 0; p < 8; ++p)
                    acc[p] += ww * r[j + ky][3 + p + kx];
            }
        }
        if (OBF) {
            unsigned short* Ob = (unsigned short*)Out + (size_t)plane * 4096;
            int4 pk = { (int)packbf2(acc[0], acc[1]), (int)packbf2(acc[2], acc[3]),
                        (int)packbf2(acc[4], acc[5]), (int)packbf2(acc[6], acc[7]) };
            *(int4*)&Ob[(y0 + j) * 64 + x0] = pk;
            if (FI)
                *(int4*)&pl[lp0 * 4608 + (y0 + j) * 72 + x0] = pk;
        } else {
            float* Ob = (float*)Out + (size_t)plane * 4096;
            f32x4 lo = {acc[0], acc[1], acc[2], acc[3]};
            f32x4 hi = {acc[4], acc[5], acc[6], acc[7]};
            *(f32x4*)&Ob[(y0 + j) * 64 + x0]     = lo;
            *(f32x4*)&Ob[(y0 + j) * 64 + x0 + 4] = hi;
        }
    }

    if (FI) {
        __syncthreads();
        int oy = tid >> 4, ox = tid & 15;
        const float st = 63.0f / 15.0f;
        float fy = oy * st, fx = ox * st;
        int iy0 = (int)floorf(fy); int iy1 = min(iy0 + 1, 63); float wy = fy - (float)iy0;
        int ix0 = (int)floorf(fx); int ix1 = min(ix0 + 1, 63); float wx = fx - (float)ix0;
#pragma unroll
        for (int lpp = 0; lpp < 2; ++lpp) {
            const unsigned short* Pb = pl + lpp * 4608;
            float v00 = bf2f(Pb[iy0 * 72 + ix0]), v01 = bf2f(Pb[iy0 * 72 + ix1]);
            float v10 = bf2f(Pb[iy1 * 72 + ix0]), v11 = bf2f(Pb[iy1 * 72 + ix1]);
            TR[(size_t)(blockIdx.x * 2 + lpp) * 256 + tid] =
                (1.f - wy) * ((1.f - wx) * v00 + wx * v01) +
                wy         * ((1.f - wx) * v10 + wx * v11);
        }
    }
}

// ---------------------------------------------------------------------------
// bf16 MFMA GEMM body (device fn; LDS passed in so co-dispatched paths share
// ONE 80 KB allocation): Out[b][n][m] = sum_k W[n][k]*A[b][k][m], K=256.
// W is PRE-PACKED bf16 (u16). KVH: kv epilogue writes khat/vhat directly.
// ---------------------------------------------------------------------------
template<int MODE, bool OB, bool AB, bool QHAT, bool XB, bool KVH>
static __device__ __forceinline__ void mgemm_dev(
    short* __restrict__ Ws, short* __restrict__ As,
    const void* __restrict__ A, const unsigned short* __restrict__ W,
    float* __restrict__ Out, const void* __restrict__ X,
    const float* __restrict__ g, const float* __restrict__ be,
    const float* __restrict__ mn, const float* __restrict__ vr,
    int M, int Ntot, int m0, int n0, int b)
{
    int tid = threadIdx.x;
    const float* Abf          = (const float*)A + (size_t)b * 256 * M;
    const unsigned short* Abh = (const unsigned short*)A + (size_t)b * 256 * M;

    // stage pre-packed bf16 W panel (u16x4 loads; no convert)
#pragma unroll
    for (int it = 0; it < 32; ++it) {
        int idx = it * 256 + tid;
        int n = idx >> 6, kq = idx & 63;
        u16x4 w4 = *(const u16x4*)&W[(size_t)(n0 + n) * 256 + kq * 4];
        *(u16x4*)&Ws[n * 256 + ((kq ^ swz(n)) << 2)] = w4;
    }

    constexpr bool RAW16 = AB && (MODE != 2);
    int mg = tid & 31, kg = tid >> 5;
    f32x4 rg[8];
    u16x4 rg16[8];
    auto load_tile = [&](int k0) {
#pragma unroll
        for (int half = 0; half < 2; ++half) {
#pragma unroll
            for (int i = 0; i < 4; ++i) {
                int c = k0 + kg * 4 + half * 32 + i;
                if (RAW16) {
                    rg16[half * 4 + i] = *(const u16x4*)&Abh[(size_t)c * M + m0 + mg * 4];
                } else if (AB) {  // bf16 in + bn2/relu (MODE 2)
                    u16x4 r4 = *(const u16x4*)&Abh[(size_t)c * M + m0 + mg * 4];
                    float iv = g[c] * rsqrtf(vr[c] + EPSF);
                    float ad = be[c] - mn[c] * iv;
                    f32x4 v;
#pragma unroll
                    for (int j = 0; j < 4; ++j)
                        v[j] = fmaxf(bf2f(r4[j]) * iv + ad, 0.f);
                    rg[half * 4 + i] = v;
                } else {
                    f32x4 v = *(const f32x4*)&Abf[(size_t)c * M + m0 + mg * 4];
                    if (MODE == 2) {
                        float iv = g[c] * rsqrtf(vr[c] + EPSF);
                        float ad = be[c] - mn[c] * iv;
#pragma unroll
                        for (int j = 0; j < 4; ++j) v[j] = fmaxf(v[j] * iv + ad, 0.f);
                    }
                    rg[half * 4 + i] = v;
                }
            }
        }
    };
    load_tile(0);

    int w = tid >> 6, lane = tid & 63;
    int wm = w & 1, wn = w >> 1;
    int lg = lane >> 4, lc = lane & 15;
    f32x4 acc[4][4] = {};

    for (int k0 = 0; k0 < 256; k0 += 64) {
        __syncthreads();
#pragma unroll
        for (int half = 0; half < 2; ++half) {
#pragma unroll
            for (int j = 0; j < 4; ++j) {
                int m = mg * 4 + j;
                short4v pk;
                if (RAW16) {
                    pk = short4v{ (short)rg16[half * 4 + 0][j], (short)rg16[half * 4 + 1][j],
                                  (short)rg16[half * 4 + 2][j], (short)rg16[half * 4 + 3][j] };
                } else {
                    pk = short4v{ (short)f2bf(rg[half * 4 + 0][j]), (short)f2bf(rg[half * 4 + 1][j]),
                                  (short)f2bf(rg[half * 4 + 2][j]), (short)f2bf(rg[half * 4 + 3][j]) };
                }
                *(short4v*)&As[m * 64 + (((kg + half * 8) ^ swz(m)) << 2)] = pk;
            }
        }
        __syncthreads();
        if (k0 < 192) load_tile(k0 + 64);
#pragma unroll
        for (int ksl = 0; ksl < 2; ++ksl) {
            short8 wf[4], af[4];
            int gk = (k0 + ksl * 32 + lg * 8) >> 2;
            int ga = (ksl * 32 + lg * 8) >> 2;
#pragma unroll
            for (int nt = 0; nt < 4; ++nt) {
                int n = wn * 64 + nt * 16 + lc;
                wf[nt] = *(const short8*)&Ws[n * 256 + ((gk ^ swz(n)) << 2)];
            }
#pragma unroll
            for (int mt = 0; mt < 4; ++mt) {
                int m = wm * 64 + mt * 16 + lc;
                af[mt] = *(const short8*)&As[m * 64 + ((ga ^ swz(m)) << 2)];
            }
#pragma unroll
            for (int nt = 0; nt < 4; ++nt)
#pragma unroll
                for (int mt = 0; mt < 4; ++mt)
                    acc[nt][mt] = __builtin_amdgcn_mfma_f32_16x16x32_bf16(
                        wf[nt], af[mt], acc[nt][mt], 0, 0, 0);
        }
    }

    if (QHAT) {
        __syncthreads();
        unsigned short* Os = (unsigned short*)Ws;   // [128][130]
#pragma unroll
        for (int nt = 0; nt < 4; ++nt)
#pragma unroll
            for (int mt = 0; mt < 4; ++mt)
#pragma unroll
                for (int reg = 0; reg < 4; ++reg) {
                    int nl = wn * 64 + nt * 16 + lg * 4 + reg;
                    int ml = wm * 64 + mt * 16 + lc;
                    Os[nl * 130 + ml] = f2bf(acc[nt][mt][reg] * QSCALE);
                }
        __syncthreads();
        unsigned short* Oq = (unsigned short*)Out;
        size_t hb = (size_t)(n0 >> 7) * QH_HALF_STRIDE + (size_t)(b * 8) * 65536;
#pragma unroll
        for (int it = 0; it < 4; ++it) {
            int ri = it * 256 + tid;
            int hh = ri >> 7, ml = ri & 127;
            u16x8 lo, hi;
#pragma unroll
            for (int dd = 0; dd < 8; ++dd) {
                lo[dd] = Os[(dd * 8 + hh) * 130 + ml];
                hi[dd] = Os[((dd + 8) * 8 + hh) * 130 + ml];
            }
            size_t base = hb + (size_t)hh * 65536 + (size_t)(m0 + ml) * 16;
            *(u16x8*)&Oq[base]     = lo;
            *(u16x8*)&Oq[base + 8] = hi;
        }
        return;
    }

    if (KVH) {
        __syncthreads();
        unsigned short* Os = (unsigned short*)Ws;   // [128][136]
#pragma unroll
        for (int nt = 0; nt < 4; ++nt)
#pragma unroll
            for (int mt = 0; mt < 4; ++mt)
#pragma unroll
                for (int reg = 0; reg < 4; ++reg) {
                    int nl = wn * 64 + nt * 16 + lg * 4 + reg;
                    int ml = wm * 64 + mt * 16 + lc;
                    Os[nl * 136 + ml] = f2bf(acc[nt][mt][reg]);
                }
        __syncthreads();
        if (n0 < 256) {
            unsigned short* Kh = (unsigned short*)Out;
            int dbase = n0 >> 3;
#pragma unroll
            for (int it = 0; it < 4; ++it) {
                int ri = it * 256 + tid;
                int hh = ri >> 7, ml = ri & 127;
                u16x8 lo, hi;
#pragma unroll
                for (int dd = 0; dd < 8; ++dd) {
                    lo[dd] = Os[(dd * 8 + hh) * 136 + ml];
                    hi[dd] = Os[((dd + 8) * 8 + hh) * 136 + ml];
                }
                size_t base = (size_t)(b * 8 + hh) * 8192 + (size_t)(m0 + ml) * 32 + dbase;
                *(u16x8*)&Kh[base]     = lo;
                *(u16x8*)&Kh[base + 8] = hi;
            }
        } else {
            unsigned short* Vh = (unsigned short*)const_cast<void*>(X);
            int dbase = (n0 - 256) >> 3;
#pragma unroll
            for (int it = 0; it < 8; ++it) {
                int ri = it * 256 + tid;
                int hh = ri >> 8;
                int dd = (ri >> 4) & 15;
                int kc = ri & 15;
                u16x8 v = *(const u16x8*)&Os[(dd * 8 + hh) * 136 + kc * 8];
                *(u16x8*)&Vh[(size_t)(b * 8 + hh) * 8192 + (size_t)(dbase + dd) * 256 + m0 + kc * 8] = v;
            }
        }
        return;
    }

    size_t ob = (size_t)b * Ntot * M;
#pragma unroll
    for (int nt = 0; nt < 4; ++nt) {
#pragma unroll
        for (int mt = 0; mt < 4; ++mt) {
#pragma unroll
            for (int reg = 0; reg < 4; ++reg) {
                int n = n0 + wn * 64 + nt * 16 + lg * 4 + reg;
                int m = m0 + wm * 64 + mt * 16 + lc;
                size_t addr = ob + (size_t)n * M + m;
                float v = acc[nt][mt][reg];
                if (MODE >= 1) {
                    float xv = XB ? bf2f(((const unsigned short*)X)[addr])
                                  : ((const float*)X)[addr];
                    v += xv;
                }
                if (OB) ((unsigned short*)Out)[addr] = f2bf(v);
                else    Out[addr] = v;
            }
        }
    }
}

// standalone wrapper (steps 7, 8)
template<int MODE, bool OB, bool AB, bool QHAT, bool XB>
__global__ __launch_bounds__(256) void mgemm_k(
    const void* __restrict__ A, const unsigned short* __restrict__ W,
    float* __restrict__ Out, const void* __restrict__ X,
    const float* __restrict__ g, const float* __restrict__ be,
    const float* __restrict__ mn, const float* __restrict__ vr,
    int M, int Ntot)
{
    __shared__ short Ws[128 * 256];
    __shared__ short As[128 * 64];
    mgemm_dev<MODE, OB, AB, QHAT, XB, false>(Ws, As, A, W, Out, X, g, be, mn, vr,
                                             M, Ntot, blockIdx.x * 128, blockIdx.y * 128,
                                             blockIdx.z);
}

// co-dispatched: bias table (grid-strided) + qhat GEMM (by<2)
// + kv GEMM writing khat/vhat directly (by==2, bx<8).
__global__ __launch_bounds__(256) void qkv_k(
    const unsigned short* __restrict__ T, const unsigned short* __restrict__ Wpk,
    float* __restrict__ Qhat, const float* __restrict__ TR,
    const float* __restrict__ rel, float* __restrict__ btab,
    unsigned short* __restrict__ khat, unsigned short* __restrict__ vhat)
{
    __shared__ short Ws[128 * 256];
    __shared__ short As[128 * 64];

    {
        int flat = (blockIdx.z * 3 + blockIdx.y) * 32 + blockIdx.x;
        for (int idx = flat * 256 + (int)threadIdx.x; idx < 524288; idx += 196608) {
            int h   = idx >> 16;
            int qc  = (idx >> 8) & 255;
            int key = idx & 255;
            int ay = qc >> 4, ax = qc & 15, by = key >> 4, bx = key & 15;
            int t = (ay - by + 15) * 31 + (ax - bx + 15);
            btab[idx] = rel[t * 8 + h] * QSCALE;
        }
    }

    if (blockIdx.y < 2) {
        mgemm_dev<0, true, true, true, false, false>(Ws, As, T, Wpk, Qhat, nullptr,
            nullptr, nullptr, nullptr, nullptr, 4096, 256,
            blockIdx.x * 128, blockIdx.y * 128, blockIdx.z);
    } else {
        if (blockIdx.x >= 8) return;
        mgemm_dev<0, true, false, false, false, true>(Ws, As, TR, Wpk + 256 * 256,
            (float*)khat, vhat, nullptr, nullptr, nullptr, nullptr, 256, 512,
            (blockIdx.x & 1) * 128, (blockIdx.x >> 1) * 128, blockIdx.z);
    }
}

// ---------------------------------------------------------------------------
// Flash split-K MFMA attention v10: v9 with 256 q-rows per block (grid 16)
// — halves the per-block prologue (kf/vq loads, setup) and block count;
// steady-state loop unchanged.
// ---------------------------------------------------------------------------
__global__ __launch_bounds__(256) void attn_mfma_k(
    const unsigned short* __restrict__ Qh, const unsigned short* __restrict__ Khat,
    const unsigned short* __restrict__ Vhat,
    const float* __restrict__ btab, unsigned short* __restrict__ O)
{
    __shared__ float Om[2][4][16][36];
    __shared__ float Lw[2][4][16];

    int b = blockIdx.z, h = blockIdx.y, chunk = blockIdx.x;
    int tid = threadIdx.x;
    int w = tid >> 6, lane = tid & 63;
    int lg = lane >> 4, lc = lane & 15;
    int kw = w * 64;

    const unsigned short* Kb = Khat + (size_t)(b * 8 + h) * 8192;
    const unsigned short* Vb = Vhat + (size_t)(b * 8 + h) * 8192;
    const unsigned short* Qb = Qh + (size_t)(lg >> 1) * QH_HALF_STRIDE
                                  + (size_t)(b * 8 + h) * 65536 + (lg & 1) * 8;
    unsigned short* Ob = O + (size_t)b * 256 * 4096;
    const float* bt = btab + (size_t)h * 65536;
    int rw = chunk * 256;

    int mrow = tid & 15, md = tid >> 4;

    short8 kf[4];
#pragma unroll
    for (int kt = 0; kt < 4; ++kt)
        kf[kt] = *(const short8*)&Kb[(kw + kt * 16 + lc) * 32 + lg * 8];

#if HAVE_MFMA16
    short4v vq[4][2];
#pragma unroll
    for (int kt = 0; kt < 4; ++kt) {
#pragma unroll
        for (int half = 0; half < 2; ++half)
            vq[kt][half] = *(const short4v*)&Vb[(half * 16 + lc) * 256 + kw + kt * 16 + lg * 4];
    }
#else
    int s1 = ((lg & 1) << 5) + lc;
    int s2 = s1 + 16;
    bool useOdd = (lg >> 1) != 0;
    short8 vf0[2], vf1[2];
#pragma unroll
    for (int ks = 0; ks < 2; ++ks) {
        vf0[ks] = *(const short8*)&Vb[lc * 256 + kw + ks * 32 + lg * 8];
        vf1[ks] = *(const short8*)&Vb[(16 + lc) * 256 + kw + ks * 32 + lg * 8];
    }
#endif

    auto loadin = [&](int mt, f32x4* sacc, short8& qf) {
        int r_a = rw + mt * 16 + lc;
        int qc = ((r_a >> 8) << 4) | ((r_a >> 2) & 15);
        const float* bq = bt + (size_t)qc * 256 + kw + lg * 4;
#pragma unroll
        for (int kt = 0; kt < 4; ++kt)
            sacc[kt] = *(const f32x4*)&bq[kt * 16];
        qf = *(const short8*)&Qb[(size_t)r_a * 16];
    };

    auto compute = [&](int buf, f32x4* sacc, short8 qf) {
#pragma unroll
        for (int kt = 0; kt < 4; ++kt)
            sacc[kt] = __builtin_amdgcn_mfma_f32_16x16x32_bf16(kf[kt], qf, sacc[kt], 0, 0, 0);

        float ls = 0.f;
        f32x4 o0 = {0.f, 0.f, 0.f, 0.f}, o1 = {0.f, 0.f, 0.f, 0.f};

#if HAVE_MFMA16
#pragma unroll
        for (int kt = 0; kt < 4; ++kt) {
            float p0 = fexp2(sacc[kt][0]);
            float p1 = fexp2(sacc[kt][1]);
            float p2 = fexp2(sacc[kt][2]);
            float p3 = fexp2(sacc[kt][3]);
            ls += (p0 + p1) + (p2 + p3);
            int2 pi = { (int)packbf2(p0, p1), (int)packbf2(p2, p3) };
            short4v pa = *(short4v*)&pi;
            o0 = __builtin_amdgcn_mfma_f32_16x16x16bf16_1k(pa, vq[kt][0], o0, 0, 0, 0);
            o1 = __builtin_amdgcn_mfma_f32_16x16x16bf16_1k(pa, vq[kt][1], o1, 0, 0, 0);
        }
        ls += __shfl_xor(ls, 16);
        ls += __shfl_xor(ls, 32);
#pragma unroll
        for (int reg = 0; reg < 4; ++reg) {
            Om[buf][w][lg * 4 + reg][lc]      = o0[reg];
            Om[buf][w][lg * 4 + reg][16 + lc] = o1[reg];
        }
#else
        unsigned plo[4], phi[4];
#pragma unroll
        for (int kt = 0; kt < 4; ++kt) {
            float p0 = fexp2(sacc[kt][0]);
            float p1 = fexp2(sacc[kt][1]);
            float p2 = fexp2(sacc[kt][2]);
            float p3 = fexp2(sacc[kt][3]);
            ls += (p0 + p1) + (p2 + p3);
            plo[kt] = packbf2(p0, p1);
            phi[kt] = packbf2(p2, p3);
        }
        ls += __shfl_xor(ls, 16);
        ls += __shfl_xor(ls, 32);
#pragma unroll
        for (int ks = 0; ks < 2; ++ks) {
            int eA = __shfl((int)plo[2 * ks], s1), oA = __shfl((int)plo[2 * ks + 1], s1);
            int eB = __shfl((int)phi[2 * ks], s1), oB = __shfl((int)phi[2 * ks + 1], s1);
            int eC = __shfl((int)plo[2 * ks], s2), oC = __shfl((int)plo[2 * ks + 1], s2);
            int eD = __shfl((int)phi[2 * ks], s2), oD = __shfl((int)phi[2 * ks + 1], s2);
            int4 pi = { useOdd ? oA : eA, useOdd ? oB : eB,
                        useOdd ? oC : eC, useOdd ? oD : eD };
            short8 pf = *(short8*)&pi;
            o0 = __builtin_amdgcn_mfma_f32_16x16x32_bf16(vf0[ks], pf, o0, 0, 0, 0);
            o1 = __builtin_amdgcn_mfma_f32_16x16x32_bf16(vf1[ks], pf, o1, 0, 0, 0);
        }
        *(f32x4*)&Om[buf][w][lc][lg * 4]      = o0;
        *(f32x4*)&Om[buf][w][lc][16 + lg * 4] = o1;
#endif
        if (lg == 0) Lw[buf][w][lc] = ls;
    };

    auto merge = [&](int mt, int buf) {
        int rbase = rw + mt * 16;
        float L = Lw[buf][0][mrow] + Lw[buf][1][mrow]
                + Lw[buf][2][mrow] + Lw[buf][3][mrow];
        float inv = __builtin_amdgcn_rcpf(L);
        float a0 = Om[buf][0][mrow][md] + Om[buf][1][mrow][md]
                 + Om[buf][2][mrow][md] + Om[buf][3][mrow][md];
        float a1 = Om[buf][0][mrow][md + 16] + Om[buf][1][mrow][md + 16]
                 + Om[buf][2][mrow][md + 16] + Om[buf][3][mrow][md + 16];
        unsigned pk = packbf2(a0 * inv, a1 * inv);
        Ob[(size_t)(md * 8 + h) * 4096 + rbase + mrow]        = (unsigned short)pk;
        Ob[(size_t)((md + 16) * 8 + h) * 4096 + rbase + mrow] = (unsigned short)(pk >> 16);
    };

    f32x4 sc[4];
    short8 qc_;
    loadin(0, sc, qc_);
    compute(0, sc, qc_);
    f32x4 sn[4];
    short8 qn;
    for (int mt = 0; mt < 16; ++mt) {
        if (mt < 15) loadin(mt + 1, sn, qn);   // global loads issued PRE-barrier
        lgkm_barrier();                         // Om[mt&1] LDS-visible
        if (mt < 15) compute((mt + 1) & 1, sn, qn);
        merge(mt, mt & 1);
    }
}

// ---------------------------------------------------------------------------
extern "C" void kernel_launch(void* const* d_in, const int* in_sizes, int n_in,
                              void* d_out, int out_size, void* d_ws, size_t ws_size,
                              hipStream_t stream)
{
    const float* x       = (const float*)d_in[0];
    const float* bn1_g   = (const float*)d_in[1];
    const float* bn1_b   = (const float*)d_in[2];
    const float* bn1_m   = (const float*)d_in[3];
    const float* bn1_v   = (const float*)d_in[4];
    const float* qkv_dw  = (const float*)d_in[5];
    const float* qkv_pw  = (const float*)d_in[6];
    const float* out_dw  = (const float*)d_in[7];
    const float* out_pw  = (const float*)d_in[8];
    const float* rel     = (const float*)d_in[9];
    const float* bn2_g   = (const float*)d_in[10];
    const float* bn2_b   = (const float*)d_in[11];
    const float* bn2_m   = (const float*)d_in[12];
    const float* bn2_v   = (const float*)d_in[13];
    const float* mlp_w   = (const float*)d_in[14];
    float* out = (float*)d_out;

    float* ws = (float*)d_ws;
    float* t    = ws;                             // BUF0: t(bf16) / o(bf16) / a(bf16)
    float* q    = ws + (size_t)8 * 1024 * 1024;   // BUF1: qhat(bf16) / t2(bf16)
    float* tr   = ws + (size_t)16 * 1024 * 1024;  // 524288 f32
    float* btab = tr + 524288;                    // f32 bias table (2 MB)
    float* khat = btab + 524288;                  // bf16 [64][256][32] (1 MB)
    float* vhat = khat + 262144;                  // bf16 [64][32][256] (1 MB)
    float* wpkf = vhat + 262144;                  // bf16 packed weights (640 KB)
    unsigned short* wpk = (unsigned short*)wpkf;
    float* o   = t;
    float* t2  = q;
    float* a   = t;

    // 1. t = dwconv3(bn1(x)) + fused interp -> tr + weight pack   bf16 out
    dwconv_k<true, false, true, true><<<dim3(1024), 256, 2 * 64 * 72 * 2, stream>>>(
        x, qkv_dw, bn1_g, bn1_b, bn1_m, bn1_v, t, tr,
        qkv_pw, out_pw, mlp_w, wpk);

    // 2+4+4b. co-dispatched: bias table + qhat GEMM + kv GEMM -> khat/vhat
    qkv_k<<<dim3(32, 3, 8), 256, 0, stream>>>(
        (const unsigned short*)t, wpk, q, tr, rel, btab,
        (unsigned short*)khat, (unsigned short*)vhat);

    // 5. o = flash split-K attention v10  bf16 out (overwrites t)
    attn_mfma_k<<<dim3(16, 8, 8), 256, 0, stream>>>(
        (const unsigned short*)q, (const unsigned short*)khat,
        (const unsigned short*)vhat, btab, (unsigned short*)o);

    // 6. t2 = dwconv3(o)              bf16 in, bf16 out (overwrites qhat)
    dwconv_k<false, true, true, false><<<dim3(1024), 256, 0, stream>>>(
        o, out_dw, nullptr, nullptr, nullptr, nullptr, t2, nullptr,
        nullptr, nullptr, nullptr, nullptr);

    // 7. a = out_pw * t2 + x          bf16 in, bf16 out (overwrites o)
    mgemm_k<1, true, true, false, false><<<dim3(32, 2, 8), 256, 0, stream>>>(
        t2, wpk + 196608, (float*)a, x, nullptr, nullptr, nullptr, nullptr,
        4096, 256);

    // 8. out = mlp_w * relu(bn2(a)) + a   bf16 in (bn2+relu in staging),
    //    residual X = a (bf16), f32 out
    mgemm_k<2, false, true, false, true><<<dim3(32, 2, 8), 256, 0, stream>>>(
        a, wpk + 262144, out, a, bn2_g, bn2_b, bn2_m, bn2_v,
        4096, 256);
}

// Round 28
// 113.027 us; speedup vs baseline: 1.0121x; 1.0121x over previous
//
#include <hip/hip_runtime.h>
#include <hip/hip_bf16.h>
#include <math.h>

#define EPSF 1e-5f

typedef float f32x4 __attribute__((ext_vector_type(4)));
typedef short short8 __attribute__((ext_vector_type(8)));
typedef short short4v __attribute__((ext_vector_type(4)));
typedef unsigned short u16x4 __attribute__((ext_vector_type(4)));
typedef unsigned short u16x8 __attribute__((ext_vector_type(8)));

#if defined(__has_builtin)
#if __has_builtin(__builtin_amdgcn_mfma_f32_16x16x16bf16_1k)
#define HAVE_MFMA16 1
#endif
#endif
#ifndef HAVE_MFMA16
#define HAVE_MFMA16 0
#endif

static __device__ __forceinline__ unsigned short f2bf(float f) {
    unsigned u = __float_as_uint(f);
    u = (u + 0x7FFF + ((u >> 16) & 1)) >> 16;
    return (unsigned short)u;
}

static __device__ __forceinline__ float bf2f(unsigned short u) {
    return __uint_as_float((unsigned)u << 16);
}

static __device__ __forceinline__ unsigned packbf2(float a, float b) {
    __hip_bfloat162 t = __float22bfloat162_rn(float2{a, b});
    union { __hip_bfloat162 v; unsigned u; } cv;
    cv.v = t;
    return cv.u;
}

// raw v_exp_f32 — NO libm wrapper (exp2f carries denormal handling)
static __device__ __forceinline__ float fexp2(float x) {
    return __builtin_amdgcn_exp2f(x);
}

// Barrier that drains ONLY LDS (lgkmcnt); "memory" clobber orders all
// memory ops. NO sched_barrier so the next tile's global loads can hoist.
static __device__ __forceinline__ void lgkm_barrier() {
    asm volatile("s_waitcnt lgkmcnt(0)\n\ts_barrier" ::: "memory");
}

// XOR-swizzle: spreads 8-byte granules of a row across banks; keeps 16B pairs.
static __device__ __forceinline__ int swz(int r) { return ((r ^ (r >> 2)) & 7) << 1; }

#define ATTN_SCALE 0.17677669529663687f   // 32^-0.5
#define LOG2E      1.4426950408889634f
#define QSCALE     (ATTN_SCALE * LOG2E)   // folded so p = exp2(s) directly

// qhat layout: [half(2)][bh(64)][row(4096)][16 dims]  (bf16)
#define QH_HALF_STRIDE 4194304   // 64*4096*16
// packed bf16 weights: qkv_pw(196608) | out_pw(65536) | mlp_w(65536)
#define WPK_TOTAL 327680

// ---------------------------------------------------------------------------
// Depthwise 3x3 conv (SAME), vectorized 4x8 tile/thread.
// FI: fuse bilinear 64->16 interp of this block's 2 planes + one-time
// grid-strided f32->bf16 weight pack (Wsrc layout: qkv_pw|out_pw|mlp_w).
// ---------------------------------------------------------------------------
template<bool BN, bool IB, bool OBF, bool FI>
__global__ __launch_bounds__(256) void dwconv_k(
    const void* __restrict__ X, const float* __restrict__ DW,
    const float* __restrict__ g, const float* __restrict__ be,
    const float* __restrict__ mn, const float* __restrict__ vr,
    void* __restrict__ Out, float* __restrict__ TR,
    const float* __restrict__ W1, const float* __restrict__ W2,
    const float* __restrict__ W3, unsigned short* __restrict__ Wpk)
{
    extern __shared__ unsigned short pl[];   // FI: [2][64][72] ushort
    int tid = threadIdx.x;

    if (FI) {
        // weight pack: grid-stride over 327680 elements (1024 blocks)
        for (int idx = blockIdx.x * 256 + tid; idx < WPK_TOTAL; idx += 262144) {
            float v = (idx < 196608) ? W1[idx]
                    : (idx < 262144) ? W2[idx - 196608]
                                     : W3[idx - 262144];
            Wpk[idx] = f2bf(v);
        }
    }

    int lp0 = tid >> 7;
    int plane = blockIdx.x * 2 + lp0;
    int c = plane & 255;
    float inv = 1.f, ad = 0.f;
    if (BN) {
        inv = g[c] * rsqrtf(vr[c] + EPSF);
        ad  = be[c] - mn[c] * inv;
    }
    float w[9];
#pragma unroll
    for (int i = 0; i < 9; ++i) w[i] = DW[c * 9 + i];
    const float* Xf          = (const float*)X + (size_t)plane * 4096;
    const unsigned short* Xh = (const unsigned short*)X + (size_t)plane * 4096;
    int u  = tid & 127;
    int y0 = (u >> 3) * 4;
    int x0 = (u & 7) * 8;

    float r[6][16];
#pragma unroll
    for (int rr = 0; rr < 6; ++rr) {
        int yy = y0 + rr - 1;
        bool rv = (unsigned)yy < 64u;
#pragma unroll
        for (int gq = 0; gq < 4; ++gq) {
            int xx = x0 - 4 + gq * 4;
            f32x4 v = {0.f, 0.f, 0.f, 0.f};
            if (rv && (unsigned)xx < 64u) {
                if (IB) {
                    u16x4 u4 = *(const u16x4*)&Xh[yy * 64 + xx];
                    v[0] = bf2f(u4[0]); v[1] = bf2f(u4[1]);
                    v[2] = bf2f(u4[2]); v[3] = bf2f(u4[3]);
                } else {
                    v = *(const f32x4*)&Xf[yy * 64 + xx];
                }
                if (BN) {
#pragma unroll
                    for (int j = 0; j < 4; ++j) v[j] = v[j] * inv + ad;
                }
            }
            r[rr][gq * 4 + 0] = v[0]; r[rr][gq * 4 + 1] = v[1];
            r[rr][gq * 4 + 2] = v[2]; r[rr][gq * 4 + 3] = v[3];
        }
    }

#pragma unroll
    for (int j = 0; j < 4; ++j) {
        float acc[8] = {};
#pragma unroll
        for (int ky = 0; ky < 3; ++ky) {
#pragma unroll
            for (int kx = 0; kx < 3; ++kx) {
                float ww = w[ky * 3 + kx];
#pragma unroll
                for (int p = 0; p < 8; ++p)
                    acc[p] += ww * r[j + ky][3 + p + kx];
            }
        }
        if (OBF) {
            unsigned short* Ob = (unsigned short*)Out + (size_t)plane * 4096;
            int4 pk = { (int)packbf2(acc[0], acc[1]), (int)packbf2(acc[2], acc[3]),
                        (int)packbf2(acc[4], acc[5]), (int)packbf2(acc[6], acc[7]) };
            *(int4*)&Ob[(y0 + j) * 64 + x0] = pk;
            if (FI)
                *(int4*)&pl[lp0 * 4608 + (y0 + j) * 72 + x0] = pk;
        } else {
            float* Ob = (float*)Out + (size_t)plane * 4096;
            f32x4 lo = {acc[0], acc[1], acc[2], acc[3]};
            f32x4 hi = {acc[4], acc[5], acc[6], acc[7]};
            *(f32x4*)&Ob[(y0 + j) * 64 + x0]     = lo;
            *(f32x4*)&Ob[(y0 + j) * 64 + x0 + 4] = hi;
        }
    }

    if (FI) {
        __syncthreads();
        int oy = tid >> 4, ox = tid & 15;
        const float st = 63.0f / 15.0f;
        float fy = oy * st, fx = ox * st;
        int iy0 = (int)floorf(fy); int iy1 = min(iy0 + 1, 63); float wy = fy - (float)iy0;
        int ix0 = (int)floorf(fx); int ix1 = min(ix0 + 1, 63); float wx = fx - (float)ix0;
#pragma unroll
        for (int lpp = 0; lpp < 2; ++lpp) {
            const unsigned short* Pb = pl + lpp * 4608;
            float v00 = bf2f(Pb[iy0 * 72 + ix0]), v01 = bf2f(Pb[iy0 * 72 + ix1]);
            float v10 = bf2f(Pb[iy1 * 72 + ix0]), v11 = bf2f(Pb[iy1 * 72 + ix1]);
            TR[(size_t)(blockIdx.x * 2 + lpp) * 256 + tid] =
                (1.f - wy) * ((1.f - wx) * v00 + wx * v01) +
                wy         * ((1.f - wx) * v10 + wx * v11);
        }
    }
}

// ---------------------------------------------------------------------------
// bf16 MFMA GEMM body (device fn; LDS passed in so co-dispatched paths share
// ONE 80 KB allocation): Out[b][n][m] = sum_k W[n][k]*A[b][k][m], K=256.
// W is PRE-PACKED bf16 (u16). KVH: kv epilogue writes khat/vhat directly.
// ---------------------------------------------------------------------------
template<int MODE, bool OB, bool AB, bool QHAT, bool XB, bool KVH>
static __device__ __forceinline__ void mgemm_dev(
    short* __restrict__ Ws, short* __restrict__ As,
    const void* __restrict__ A, const unsigned short* __restrict__ W,
    float* __restrict__ Out, const void* __restrict__ X,
    const float* __restrict__ g, const float* __restrict__ be,
    const float* __restrict__ mn, const float* __restrict__ vr,
    int M, int Ntot, int m0, int n0, int b)
{
    int tid = threadIdx.x;
    const float* Abf          = (const float*)A + (size_t)b * 256 * M;
    const unsigned short* Abh = (const unsigned short*)A + (size_t)b * 256 * M;

    // stage pre-packed bf16 W panel (u16x4 loads; no convert)
#pragma unroll
    for (int it = 0; it < 32; ++it) {
        int idx = it * 256 + tid;
        int n = idx >> 6, kq = idx & 63;
        u16x4 w4 = *(const u16x4*)&W[(size_t)(n0 + n) * 256 + kq * 4];
        *(u16x4*)&Ws[n * 256 + ((kq ^ swz(n)) << 2)] = w4;
    }

    constexpr bool RAW16 = AB && (MODE != 2);
    int mg = tid & 31, kg = tid >> 5;
    f32x4 rg[8];
    u16x4 rg16[8];
    auto load_tile = [&](int k0) {
#pragma unroll
        for (int half = 0; half < 2; ++half) {
#pragma unroll
            for (int i = 0; i < 4; ++i) {
                int c = k0 + kg * 4 + half * 32 + i;
                if (RAW16) {
                    rg16[half * 4 + i] = *(const u16x4*)&Abh[(size_t)c * M + m0 + mg * 4];
                } else if (AB) {  // bf16 in + bn2/relu (MODE 2)
                    u16x4 r4 = *(const u16x4*)&Abh[(size_t)c * M + m0 + mg * 4];
                    float iv = g[c] * rsqrtf(vr[c] + EPSF);
                    float ad = be[c] - mn[c] * iv;
                    f32x4 v;
#pragma unroll
                    for (int j = 0; j < 4; ++j)
                        v[j] = fmaxf(bf2f(r4[j]) * iv + ad, 0.f);
                    rg[half * 4 + i] = v;
                } else {
                    f32x4 v = *(const f32x4*)&Abf[(size_t)c * M + m0 + mg * 4];
                    if (MODE == 2) {
                        float iv = g[c] * rsqrtf(vr[c] + EPSF);
                        float ad = be[c] - mn[c] * iv;
#pragma unroll
                        for (int j = 0; j < 4; ++j) v[j] = fmaxf(v[j] * iv + ad, 0.f);
                    }
                    rg[half * 4 + i] = v;
                }
            }
        }
    };
    load_tile(0);

    int w = tid >> 6, lane = tid & 63;
    int wm = w & 1, wn = w >> 1;
    int lg = lane >> 4, lc = lane & 15;
    f32x4 acc[4][4] = {};

    for (int k0 = 0; k0 < 256; k0 += 64) {
        __syncthreads();
#pragma unroll
        for (int half = 0; half < 2; ++half) {
#pragma unroll
            for (int j = 0; j < 4; ++j) {
                int m = mg * 4 + j;
                short4v pk;
                if (RAW16) {
                    pk = short4v{ (short)rg16[half * 4 + 0][j], (short)rg16[half * 4 + 1][j],
                                  (short)rg16[half * 4 + 2][j], (short)rg16[half * 4 + 3][j] };
                } else {
                    pk = short4v{ (short)f2bf(rg[half * 4 + 0][j]), (short)f2bf(rg[half * 4 + 1][j]),
                                  (short)f2bf(rg[half * 4 + 2][j]), (short)f2bf(rg[half * 4 + 3][j]) };
                }
                *(short4v*)&As[m * 64 + (((kg + half * 8) ^ swz(m)) << 2)] = pk;
            }
        }
        __syncthreads();
        if (k0 < 192) load_tile(k0 + 64);
#pragma unroll
        for (int ksl = 0; ksl < 2; ++ksl) {
            short8 wf[4], af[4];
            int gk = (k0 + ksl * 32 + lg * 8) >> 2;
            int ga = (ksl * 32 + lg * 8) >> 2;
#pragma unroll
            for (int nt = 0; nt < 4; ++nt) {
                int n = wn * 64 + nt * 16 + lc;
                wf[nt] = *(const short8*)&Ws[n * 256 + ((gk ^ swz(n)) << 2)];
            }
#pragma unroll
            for (int mt = 0; mt < 4; ++mt) {
                int m = wm * 64 + mt * 16 + lc;
                af[mt] = *(const short8*)&As[m * 64 + ((ga ^ swz(m)) << 2)];
            }
#pragma unroll
            for (int nt = 0; nt < 4; ++nt)
#pragma unroll
                for (int mt = 0; mt < 4; ++mt)
                    acc[nt][mt] = __builtin_amdgcn_mfma_f32_16x16x32_bf16(
                        wf[nt], af[mt], acc[nt][mt], 0, 0, 0);
        }
    }

    if (QHAT) {
        __syncthreads();
        unsigned short* Os = (unsigned short*)Ws;   // [128][130]
#pragma unroll
        for (int nt = 0; nt < 4; ++nt)
#pragma unroll
            for (int mt = 0; mt < 4; ++mt)
#pragma unroll
                for (int reg = 0; reg < 4; ++reg) {
                    int nl = wn * 64 + nt * 16 + lg * 4 + reg;
                    int ml = wm * 64 + mt * 16 + lc;
                    Os[nl * 130 + ml] = f2bf(acc[nt][mt][reg] * QSCALE);
                }
        __syncthreads();
        unsigned short* Oq = (unsigned short*)Out;
        size_t hb = (size_t)(n0 >> 7) * QH_HALF_STRIDE + (size_t)(b * 8) * 65536;
#pragma unroll
        for (int it = 0; it < 4; ++it) {
            int ri = it * 256 + tid;
            int hh = ri >> 7, ml = ri & 127;
            u16x8 lo, hi;
#pragma unroll
            for (int dd = 0; dd < 8; ++dd) {
                lo[dd] = Os[(dd * 8 + hh) * 130 + ml];
                hi[dd] = Os[((dd + 8) * 8 + hh) * 130 + ml];
            }
            size_t base = hb + (size_t)hh * 65536 + (size_t)(m0 + ml) * 16;
            *(u16x8*)&Oq[base]     = lo;
            *(u16x8*)&Oq[base + 8] = hi;
        }
        return;
    }

    if (KVH) {
        __syncthreads();
        unsigned short* Os = (unsigned short*)Ws;   // [128][136]
#pragma unroll
        for (int nt = 0; nt < 4; ++nt)
#pragma unroll
            for (int mt = 0; mt < 4; ++mt)
#pragma unroll
                for (int reg = 0; reg < 4; ++reg) {
                    int nl = wn * 64 + nt * 16 + lg * 4 + reg;
                    int ml = wm * 64 + mt * 16 + lc;
                    Os[nl * 136 + ml] = f2bf(acc[nt][mt][reg]);
                }
        __syncthreads();
        if (n0 < 256) {
            unsigned short* Kh = (unsigned short*)Out;
            int dbase = n0 >> 3;
#pragma unroll
            for (int it = 0; it < 4; ++it) {
                int ri = it * 256 + tid;
                int hh = ri >> 7, ml = ri & 127;
                u16x8 lo, hi;
#pragma unroll
                for (int dd = 0; dd < 8; ++dd) {
                    lo[dd] = Os[(dd * 8 + hh) * 136 + ml];
                    hi[dd] = Os[((dd + 8) * 8 + hh) * 136 + ml];
                }
                size_t base = (size_t)(b * 8 + hh) * 8192 + (size_t)(m0 + ml) * 32 + dbase;
                *(u16x8*)&Kh[base]     = lo;
                *(u16x8*)&Kh[base + 8] = hi;
            }
        } else {
            unsigned short* Vh = (unsigned short*)const_cast<void*>(X);
            int dbase = (n0 - 256) >> 3;
#pragma unroll
            for (int it = 0; it < 8; ++it) {
                int ri = it * 256 + tid;
                int hh = ri >> 8;
                int dd = (ri >> 4) & 15;
                int kc = ri & 15;
                u16x8 v = *(const u16x8*)&Os[(dd * 8 + hh) * 136 + kc * 8];
                *(u16x8*)&Vh[(size_t)(b * 8 + hh) * 8192 + (size_t)(dbase + dd) * 256 + m0 + kc * 8] = v;
            }
        }
        return;
    }

    size_t ob = (size_t)b * Ntot * M;
#pragma unroll
    for (int nt = 0; nt < 4; ++nt) {
#pragma unroll
        for (int mt = 0; mt < 4; ++mt) {
#pragma unroll
            for (int reg = 0; reg < 4; ++reg) {
                int n = n0 + wn * 64 + nt * 16 + lg * 4 + reg;
                int m = m0 + wm * 64 + mt * 16 + lc;
                size_t addr = ob + (size_t)n * M + m;
                float v = acc[nt][mt][reg];
                if (MODE >= 1) {
                    float xv = XB ? bf2f(((const unsigned short*)X)[addr])
                                  : ((const float*)X)[addr];
                    v += xv;
                }
                if (OB) ((unsigned short*)Out)[addr] = f2bf(v);
                else    Out[addr] = v;
            }
        }
    }
}

// standalone wrapper (steps 7, 8)
template<int MODE, bool OB, bool AB, bool QHAT, bool XB>
__global__ __launch_bounds__(256) void mgemm_k(
    const void* __restrict__ A, const unsigned short* __restrict__ W,
    float* __restrict__ Out, const void* __restrict__ X,
    const float* __restrict__ g, const float* __restrict__ be,
    const float* __restrict__ mn, const float* __restrict__ vr,
    int M, int Ntot)
{
    __shared__ short Ws[128 * 256];
    __shared__ short As[128 * 64];
    mgemm_dev<MODE, OB, AB, QHAT, XB, false>(Ws, As, A, W, Out, X, g, be, mn, vr,
                                             M, Ntot, blockIdx.x * 128, blockIdx.y * 128,
                                             blockIdx.z);
}

// co-dispatched: bias table (grid-strided) + qhat GEMM (by<2)
// + kv GEMM writing khat/vhat directly (by==2, bx<8).
__global__ __launch_bounds__(256) void qkv_k(
    const unsigned short* __restrict__ T, const unsigned short* __restrict__ Wpk,
    float* __restrict__ Qhat, const float* __restrict__ TR,
    const float* __restrict__ rel, float* __restrict__ btab,
    unsigned short* __restrict__ khat, unsigned short* __restrict__ vhat)
{
    __shared__ short Ws[128 * 256];
    __shared__ short As[128 * 64];

    {
        int flat = (blockIdx.z * 3 + blockIdx.y) * 32 + blockIdx.x;
        for (int idx = flat * 256 + (int)threadIdx.x; idx < 524288; idx += 196608) {
            int h   = idx >> 16;
            int qc  = (idx >> 8) & 255;
            int key = idx & 255;
            int ay = qc >> 4, ax = qc & 15, by = key >> 4, bx = key & 15;
            int t = (ay - by + 15) * 31 + (ax - bx + 15);
            btab[idx] = rel[t * 8 + h] * QSCALE;
        }
    }

    if (blockIdx.y < 2) {
        mgemm_dev<0, true, true, true, false, false>(Ws, As, T, Wpk, Qhat, nullptr,
            nullptr, nullptr, nullptr, nullptr, 4096, 256,
            blockIdx.x * 128, blockIdx.y * 128, blockIdx.z);
    } else {
        if (blockIdx.x >= 8) return;
        mgemm_dev<0, true, false, false, false, true>(Ws, As, TR, Wpk + 256 * 256,
            (float*)khat, vhat, nullptr, nullptr, nullptr, nullptr, 256, 512,
            (blockIdx.x & 1) * 128, (blockIdx.x >> 1) * 128, blockIdx.z);
    }
}

// ---------------------------------------------------------------------------
// Flash split-K MFMA attention v9 (round-26 best): prefetch + half-split
// qhat reads, 128 q-rows/block, grid (32, 8, 8).
// ---------------------------------------------------------------------------
__global__ __launch_bounds__(256) void attn_mfma_k(
    const unsigned short* __restrict__ Qh, const unsigned short* __restrict__ Khat,
    const unsigned short* __restrict__ Vhat,
    const float* __restrict__ btab, unsigned short* __restrict__ O)
{
    __shared__ float Om[2][4][16][36];
    __shared__ float Lw[2][4][16];

    int b = blockIdx.z, h = blockIdx.y, chunk = blockIdx.x;
    int tid = threadIdx.x;
    int w = tid >> 6, lane = tid & 63;
    int lg = lane >> 4, lc = lane & 15;
    int kw = w * 64;

    const unsigned short* Kb = Khat + (size_t)(b * 8 + h) * 8192;
    const unsigned short* Vb = Vhat + (size_t)(b * 8 + h) * 8192;
    const unsigned short* Qb = Qh + (size_t)(lg >> 1) * QH_HALF_STRIDE
                                  + (size_t)(b * 8 + h) * 65536 + (lg & 1) * 8;
    unsigned short* Ob = O + (size_t)b * 256 * 4096;
    const float* bt = btab + (size_t)h * 65536;
    int rw = chunk * 128;

    int mrow = tid & 15, md = tid >> 4;

    short8 kf[4];
#pragma unroll
    for (int kt = 0; kt < 4; ++kt)
        kf[kt] = *(const short8*)&Kb[(kw + kt * 16 + lc) * 32 + lg * 8];

#if HAVE_MFMA16
    short4v vq[4][2];
#pragma unroll
    for (int kt = 0; kt < 4; ++kt) {
#pragma unroll
        for (int half = 0; half < 2; ++half)
            vq[kt][half] = *(const short4v*)&Vb[(half * 16 + lc) * 256 + kw + kt * 16 + lg * 4];
    }
#else
    int s1 = ((lg & 1) << 5) + lc;
    int s2 = s1 + 16;
    bool useOdd = (lg >> 1) != 0;
    short8 vf0[2], vf1[2];
#pragma unroll
    for (int ks = 0; ks < 2; ++ks) {
        vf0[ks] = *(const short8*)&Vb[lc * 256 + kw + ks * 32 + lg * 8];
        vf1[ks] = *(const short8*)&Vb[(16 + lc) * 256 + kw + ks * 32 + lg * 8];
    }
#endif

    auto loadin = [&](int mt, f32x4* sacc, short8& qf) {
        int r_a = rw + mt * 16 + lc;
        int qc = ((r_a >> 8) << 4) | ((r_a >> 2) & 15);
        const float* bq = bt + (size_t)qc * 256 + kw + lg * 4;
#pragma unroll
        for (int kt = 0; kt < 4; ++kt)
            sacc[kt] = *(const f32x4*)&bq[kt * 16];
        qf = *(const short8*)&Qb[(size_t)r_a * 16];
    };

    auto compute = [&](int buf, f32x4* sacc, short8 qf) {
#pragma unroll
        for (int kt = 0; kt < 4; ++kt)
            sacc[kt] = __builtin_amdgcn_mfma_f32_16x16x32_bf16(kf[kt], qf, sacc[kt], 0, 0, 0);

        float ls = 0.f;
        f32x4 o0 = {0.f, 0.f, 0.f, 0.f}, o1 = {0.f, 0.f, 0.f, 0.f};

#if HAVE_MFMA16
#pragma unroll
        for (int kt = 0; kt < 4; ++kt) {
            float p0 = fexp2(sacc[kt][0]);
            float p1 = fexp2(sacc[kt][1]);
            float p2 = fexp2(sacc[kt][2]);
            float p3 = fexp2(sacc[kt][3]);
            ls += (p0 + p1) + (p2 + p3);
            int2 pi = { (int)packbf2(p0, p1), (int)packbf2(p2, p3) };
            short4v pa = *(short4v*)&pi;
            o0 = __builtin_amdgcn_mfma_f32_16x16x16bf16_1k(pa, vq[kt][0], o0, 0, 0, 0);
            o1 = __builtin_amdgcn_mfma_f32_16x16x16bf16_1k(pa, vq[kt][1], o1, 0, 0, 0);
        }
        ls += __shfl_xor(ls, 16);
        ls += __shfl_xor(ls, 32);
#pragma unroll
        for (int reg = 0; reg < 4; ++reg) {
            Om[buf][w][lg * 4 + reg][lc]      = o0[reg];
            Om[buf][w][lg * 4 + reg][16 + lc] = o1[reg];
        }
#else
        unsigned plo[4], phi[4];
#pragma unroll
        for (int kt = 0; kt < 4; ++kt) {
            float p0 = fexp2(sacc[kt][0]);
            float p1 = fexp2(sacc[kt][1]);
            float p2 = fexp2(sacc[kt][2]);
            float p3 = fexp2(sacc[kt][3]);
            ls += (p0 + p1) + (p2 + p3);
            plo[kt] = packbf2(p0, p1);
            phi[kt] = packbf2(p2, p3);
        }
        ls += __shfl_xor(ls, 16);
        ls += __shfl_xor(ls, 32);
#pragma unroll
        for (int ks = 0; ks < 2; ++ks) {
            int eA = __shfl((int)plo[2 * ks], s1), oA = __shfl((int)plo[2 * ks + 1], s1);
            int eB = __shfl((int)phi[2 * ks], s1), oB = __shfl((int)phi[2 * ks + 1], s1);
            int eC = __shfl((int)plo[2 * ks], s2), oC = __shfl((int)plo[2 * ks + 1], s2);
            int eD = __shfl((int)phi[2 * ks], s2), oD = __shfl((int)phi[2 * ks + 1], s2);
            int4 pi = { useOdd ? oA : eA, useOdd ? oB : eB,
                        useOdd ? oC : eC, useOdd ? oD : eD };
            short8 pf = *(short8*)&pi;
            o0 = __builtin_amdgcn_mfma_f32_16x16x32_bf16(vf0[ks], pf, o0, 0, 0, 0);
            o1 = __builtin_amdgcn_mfma_f32_16x16x32_bf16(vf1[ks], pf, o1, 0, 0, 0);
        }
        *(f32x4*)&Om[buf][w][lc][lg * 4]      = o0;
        *(f32x4*)&Om[buf][w][lc][16 + lg * 4] = o1;
#endif
        if (lg == 0) Lw[buf][w][lc] = ls;
    };

    auto merge = [&](int mt, int buf) {
        int rbase = rw + mt * 16;
        float L = Lw[buf][0][mrow] + Lw[buf][1][mrow]
                + Lw[buf][2][mrow] + Lw[buf][3][mrow];
        float inv = __builtin_amdgcn_rcpf(L);
        float a0 = Om[buf][0][mrow][md] + Om[buf][1][mrow][md]
                 + Om[buf][2][mrow][md] + Om[buf][3][mrow][md];
        float a1 = Om[buf][0][mrow][md + 16] + Om[buf][1][mrow][md + 16]
                 + Om[buf][2][mrow][md + 16] + Om[buf][3][mrow][md + 16];
        unsigned pk = packbf2(a0 * inv, a1 * inv);
        Ob[(size_t)(md * 8 + h) * 4096 + rbase + mrow]        = (unsigned short)pk;
        Ob[(size_t)((md + 16) * 8 + h) * 4096 + rbase + mrow] = (unsigned short)(pk >> 16);
    };

    f32x4 sc[4];
    short8 qc_;
    loadin(0, sc, qc_);
    compute(0, sc, qc_);
    f32x4 sn[4];
    short8 qn;
    for (int mt = 0; mt < 8; ++mt) {
        if (mt < 7) loadin(mt + 1, sn, qn);   // global loads issued PRE-barrier
        lgkm_barrier();                        // Om[mt&1] LDS-visible
        if (mt < 7) compute((mt + 1) & 1, sn, qn);
        merge(mt, mt & 1);
    }
}

// ---------------------------------------------------------------------------
extern "C" void kernel_launch(void* const* d_in, const int* in_sizes, int n_in,
                              void* d_out, int out_size, void* d_ws, size_t ws_size,
                              hipStream_t stream)
{
    const float* x       = (const float*)d_in[0];
    const float* bn1_g   = (const float*)d_in[1];
    const float* bn1_b   = (const float*)d_in[2];
    const float* bn1_m   = (const float*)d_in[3];
    const float* bn1_v   = (const float*)d_in[4];
    const float* qkv_dw  = (const float*)d_in[5];
    const float* qkv_pw  = (const float*)d_in[6];
    const float* out_dw  = (const float*)d_in[7];
    const float* out_pw  = (const float*)d_in[8];
    const float* rel     = (const float*)d_in[9];
    const float* bn2_g   = (const float*)d_in[10];
    const float* bn2_b   = (const float*)d_in[11];
    const float* bn2_m   = (const float*)d_in[12];
    const float* bn2_v   = (const float*)d_in[13];
    const float* mlp_w   = (const float*)d_in[14];
    float* out = (float*)d_out;

    float* ws = (float*)d_ws;
    float* t    = ws;                             // BUF0: t(bf16) / o(bf16) / a(bf16)
    float* q    = ws + (size_t)8 * 1024 * 1024;   // BUF1: qhat(bf16) / t2(bf16)
    float* tr   = ws + (size_t)16 * 1024 * 1024;  // 524288 f32
    float* btab = tr + 524288;                    // f32 bias table (2 MB)
    float* khat = btab + 524288;                  // bf16 [64][256][32] (1 MB)
    float* vhat = khat + 262144;                  // bf16 [64][32][256] (1 MB)
    float* wpkf = vhat + 262144;                  // bf16 packed weights (640 KB)
    unsigned short* wpk = (unsigned short*)wpkf;
    float* o   = t;
    float* t2  = q;
    float* a   = t;

    // 1. t = dwconv3(bn1(x)) + fused interp -> tr + weight pack   bf16 out
    dwconv_k<true, false, true, true><<<dim3(1024), 256, 2 * 64 * 72 * 2, stream>>>(
        x, qkv_dw, bn1_g, bn1_b, bn1_m, bn1_v, t, tr,
        qkv_pw, out_pw, mlp_w, wpk);

    // 2+4+4b. co-dispatched: bias table + qhat GEMM + kv GEMM -> khat/vhat
    qkv_k<<<dim3(32, 3, 8), 256, 0, stream>>>(
        (const unsigned short*)t, wpk, q, tr, rel, btab,
        (unsigned short*)khat, (unsigned short*)vhat);

    // 5. o = flash split-K attention v9  bf16 out (overwrites t)
    attn_mfma_k<<<dim3(32, 8, 8), 256, 0, stream>>>(
        (const unsigned short*)q, (const unsigned short*)khat,
        (const unsigned short*)vhat, btab, (unsigned short*)o);

    // 6. t2 = dwconv3(o)              bf16 in, bf16 out (overwrites qhat)
    dwconv_k<false, true, true, false><<<dim3(1024), 256, 0, stream>>>(
        o, out_dw, nullptr, nullptr, nullptr, nullptr, t2, nullptr,
        nullptr, nullptr, nullptr, nullptr);

    // 7. a = out_pw * t2 + x          bf16 in, bf16 out (overwrites o)
    mgemm_k<1, true, true, false, false><<<dim3(32, 2, 8), 256, 0, stream>>>(
        t2, wpk + 196608, (float*)a, x, nullptr, nullptr, nullptr, nullptr,
        4096, 256);

    // 8. out = mlp_w * relu(bn2(a)) + a   bf16 in (bn2+relu in staging),
    //    residual X = a (bf16), f32 out
    mgemm_k<2, false, true, false, true><<<dim3(32, 2, 8), 256, 0, stream>>>(
        a, wpk + 262144, out, a, bn2_g, bn2_b, bn2_m, bn2_v,
        4096, 256);
}